// Round 4
// baseline (826.166 us; speedup 1.0000x reference)
//
#include <hip/hip_runtime.h>

#define B_   16
#define T_   512
#define V_   64
#define C1_  16
#define H_   64
#define TC_  256
#define NC_  10
#define INV_N (1.0f/524288.0f)   // 1/(B*T*V)
#define INV_T (1.0f/512.0f)

// statsP layout (floats):
//   [0 .. 1215]    8 slots x 152: {sumy[16], G[136] packed upper-tri (c-major, d>=c)}
//   [1216 .. 2239] 8 slots x 128: BN2 partials {sum[64], sumsq[64]}
//   [2240..2303] aff1 scale   [2304..2367] aff1 shift   (written by k_gcn2)
//   [2368..2431] aff2 scale   [2432..2495] aff2 shift   (written by k_aff)

// ---------------------------------------------------------------- K0: adj_norm
__global__ __launch_bounds__(256) void k_adjnorm(const float* __restrict__ adj,
                                                 float* __restrict__ AnT,
                                                 float* __restrict__ statsP) {
  const int b = blockIdx.x;
  __shared__ float As[4096];
  __shared__ float dis[64];
  for (int idx = threadIdx.x; idx < 4096; idx += 256) As[idx] = adj[b * 4096 + idx];
  __syncthreads();
  if (threadIdx.x < 64) {
    const int v = threadIdx.x;
    float s = 0.f;
    #pragma unroll 8
    for (int w = 0; w < 64; ++w) s += As[v * 64 + ((w + v) & 63)];  // bank-fanned
    dis[v] = rsqrtf(s + 1e-6f);
  }
  __syncthreads();
  for (int idx = threadIdx.x; idx < 4096; idx += 256) {
    const int v = idx >> 6, w = idx & 63;
    AnT[b * 4096 + w * 64 + v] = dis[v] * As[v * 64 + w] * dis[w];
  }
  if (threadIdx.x < 140) statsP[b * 140 + threadIdx.x] = 0.f;   // zero [0,2240)
}

// ---------------------------------------------------------- K1: y = An@x (16ch)
__global__ __launch_bounds__(256) void k_gcn1(const float* __restrict__ x,
    const float* __restrict__ AnT, float* __restrict__ y) {
  const int b    = blockIdx.y;
  const int lane = threadIdx.x & 63;
  const int wq   = __builtin_amdgcn_readfirstlane(threadIdx.x >> 6);
  const float* __restrict__ At = AnT + b * 4096;
  for (int k = 0; k < 2; ++k) {
    const int t = blockIdx.x * 8 + wq * 2 + k;
    const float* __restrict__ xt = x + ((size_t)(b * T_ + t)) * V_ * C1_;
    float Y[16];
    #pragma unroll
    for (int i = 0; i < 16; ++i) Y[i] = 0.f;
    for (int w = 0; w < V_; ++w) {
      const float a = At[w * 64 + lane];
      const float* __restrict__ xr = xt + w * C1_;   // wave-uniform row
      #pragma unroll
      for (int c = 0; c < 16; ++c) Y[c] += a * xr[c];
    }
    float4* yo = (float4*)(y + (((size_t)(b * T_ + t)) * V_ + lane) * C1_);
    yo[0] = make_float4(Y[0], Y[1], Y[2], Y[3]);
    yo[1] = make_float4(Y[4], Y[5], Y[6], Y[7]);
    yo[2] = make_float4(Y[8], Y[9], Y[10], Y[11]);
    yo[3] = make_float4(Y[12], Y[13], Y[14], Y[15]);
  }
}

// ----------------------------- K1b: Gram stats. G = sum_rows y y^T, sumy.
// sum z = sumy^T.W1 + N b1 ; sum z^2 = w^T G w + 2 b1 lin + N b1^2 (folded later)
__global__ __launch_bounds__(256) void k_gram(const float* __restrict__ y,
                                              float* __restrict__ statsP) {
  const int tid = blockIdx.x * 256 + threadIdx.x;
  const float* __restrict__ yp = y + (size_t)tid * 64;   // 4 consecutive rows
  float sy[16], G[136];
  #pragma unroll
  for (int i = 0; i < 16; ++i) sy[i] = 0.f;
  #pragma unroll
  for (int i = 0; i < 136; ++i) G[i] = 0.f;
  #pragma unroll
  for (int r = 0; r < 4; ++r) {
    float v[16];
    const float4* vp = (const float4*)(yp + r * 16);
    const float4 a0 = vp[0], a1 = vp[1], a2 = vp[2], a3 = vp[3];
    v[0]=a0.x; v[1]=a0.y; v[2]=a0.z; v[3]=a0.w;
    v[4]=a1.x; v[5]=a1.y; v[6]=a1.z; v[7]=a1.w;
    v[8]=a2.x; v[9]=a2.y; v[10]=a2.z; v[11]=a2.w;
    v[12]=a3.x; v[13]=a3.y; v[14]=a3.z; v[15]=a3.w;
    #pragma unroll
    for (int c = 0; c < 16; ++c) sy[c] += v[c];
    int idx = 0;
    #pragma unroll
    for (int c = 0; c < 16; ++c)
      #pragma unroll
      for (int d = c; d < 16; ++d) { G[idx] += v[c] * v[d]; ++idx; }
  }
  // full-wave butterfly allreduce
  #pragma unroll
  for (int m = 1; m <= 32; m <<= 1) {
    #pragma unroll
    for (int i = 0; i < 16; ++i) sy[i] += __shfl_xor(sy[i], m, 64);
    #pragma unroll
    for (int i = 0; i < 136; ++i) G[i] += __shfl_xor(G[i], m, 64);
  }
  if ((threadIdx.x & 63) == 0) {
    float* sp = statsP + (blockIdx.x & 7) * 152;
    #pragma unroll
    for (int i = 0; i < 16; ++i) atomicAdd(&sp[i], sy[i]);
    #pragma unroll
    for (int i = 0; i < 136; ++i) atomicAdd(&sp[16 + i], G[i]);
  }
}

// ---------------------------------------------------------------- K2: layer 2
// Per t: y tile -> LDS (per-lane float4 loads), x1 built in regs (W1 scalar),
// An@x1 (At scalar, x1 from LDS), P transposed through the same stride-65
// buffer, P@W2 (W2 scalar). z2 + BN2 partials out.
__global__ __launch_bounds__(256) void k_gcn2(const float* __restrict__ y,
    const float* __restrict__ AnT, const float* __restrict__ w1,
    const float* __restrict__ b1, const float* __restrict__ g1,
    const float* __restrict__ be1, const float* __restrict__ w2,
    const float* __restrict__ b2, float* __restrict__ statsP,
    float* __restrict__ z2) {
  __shared__ float ybuf[64 * 17];     // 4.25 KB
  __shared__ float sbuf[64 * 65];     // 16.25 KB (x1, then P^T)
  __shared__ float gtot[152];
  __shared__ float affl[128];
  const int b    = blockIdx.y;
  const int t0   = blockIdx.x * 8;
  const int lane = threadIdx.x & 63;
  const int wq   = __builtin_amdgcn_readfirstlane(threadIdx.x >> 6);
  const int q0   = wq * 16;

  // ---- prologue: fold G partials -> aff1 (var = w^T G w/N - (lin/N)^2)
  for (int i = threadIdx.x; i < 152; i += 256) {
    float s = 0.f;
    #pragma unroll
    for (int sl = 0; sl < 8; ++sl) s += statsP[sl * 152 + i];
    gtot[i] = s;
  }
  __syncthreads();
  if (threadIdx.x < 64) {
    const int o = threadIdx.x;
    float wv[16];
    #pragma unroll
    for (int c = 0; c < 16; ++c) wv[c] = w1[c * 64 + o];
    float lin = 0.f;
    #pragma unroll
    for (int c = 0; c < 16; ++c) lin += gtot[c] * wv[c];
    float qd = 0.f;
    int idx = 16;
    #pragma unroll
    for (int c = 0; c < 16; ++c) {
      qd += gtot[idx] * wv[c] * wv[c]; ++idx;
      #pragma unroll
      for (int d = c + 1; d < 16; ++d) { qd += 2.f * gtot[idx] * wv[c] * wv[d]; ++idx; }
    }
    const float linN = lin * INV_N;
    const float mean = linN + b1[o];
    const float var  = qd * INV_N - linN * linN;
    const float sc   = g1[o] * rsqrtf(var + 1e-5f);
    const float sh   = be1[o] - mean * sc;
    affl[o] = sc; affl[64 + o] = sh;
    statsP[2240 + o] = sc; statsP[2304 + o] = sh;   // cache for k_sfl
  }
  __syncthreads();
  float asc[16], ash[16];
  #pragma unroll
  for (int i = 0; i < 16; ++i) { asc[i] = affl[q0 + i]; ash[i] = affl[64 + q0 + i]; }

  const float* __restrict__ At = AnT + b * 4096;
  float ts0[16], ts1[16];
  #pragma unroll
  for (int i = 0; i < 16; ++i) { ts0[i] = 0.f; ts1[i] = 0.f; }

  for (int tt = 0; tt < 8; ++tt) {
    const int t = t0 + tt;
    // per-lane vectorized y-tile load (1024 floats)
    const float4 yv4 = *(const float4*)(y + ((size_t)(b * T_ + t)) * 1024 + threadIdx.x * 4);
    __syncthreads();                                  // prev readers of bufs done
    { const int w = threadIdx.x >> 2, c0 = (threadIdx.x & 3) * 4;
      ybuf[w * 17 + c0 + 0] = yv4.x;
      ybuf[w * 17 + c0 + 1] = yv4.y;
      ybuf[w * 17 + c0 + 2] = yv4.z;
      ybuf[w * 17 + c0 + 3] = yv4.w; }
    __syncthreads();                                  // ybuf ready
    // build x1: row = lane, channels q0..q0+15 (W1 scalar)
    float z[16];
    #pragma unroll
    for (int i = 0; i < 16; ++i) z[i] = 0.f;
    #pragma unroll
    for (int k = 0; k < 16; ++k) {
      const float yk = ybuf[lane * 17 + k];
      #pragma unroll
      for (int i = 0; i < 16; ++i) z[i] += yk * w1[k * 64 + q0 + i];
    }
    #pragma unroll
    for (int i = 0; i < 16; ++i)
      sbuf[lane * 65 + q0 + i] = fmaxf(z[i] * asc[i] + ash[i], 0.f);
    __syncthreads();                                  // x1 ready
    // phase1: P[q0+i][c=lane] = sum_w An[q0+i][w] * x1[w][lane]  (At scalar)
    float P[16];
    #pragma unroll
    for (int i = 0; i < 16; ++i) P[i] = 0.f;
    for (int w = 0; w < 64; ++w) {
      const float xv = sbuf[w * 65 + lane];
      #pragma unroll
      for (int i = 0; i < 16; ++i) P[i] += At[w * 64 + q0 + i] * xv;
    }
    __syncthreads();                                  // all x1 reads done
    #pragma unroll
    for (int i = 0; i < 16; ++i) sbuf[(q0 + i) * 65 + lane] = P[i];
    __syncthreads();                                  // P ready
    // phase2: Z[v=lane][q0+i] = b2 + sum_c P[lane][c] * W2[c][q0+i]  (W2 scalar)
    float Z[16];
    #pragma unroll
    for (int i = 0; i < 16; ++i) Z[i] = b2[q0 + i];
    for (int c = 0; c < 64; ++c) {
      const float p = sbuf[lane * 65 + c];
      #pragma unroll
      for (int i = 0; i < 16; ++i) Z[i] += w2[c * 64 + q0 + i] * p;
    }
    #pragma unroll
    for (int i = 0; i < 16; ++i) { const float v = Z[i]; ts0[i] += v; ts1[i] += v * v; }
    float4* zo = (float4*)(z2 + (((size_t)(b * T_ + t)) * V_ + lane) * H_ + q0);
    zo[0] = make_float4(Z[0], Z[1], Z[2], Z[3]);
    zo[1] = make_float4(Z[4], Z[5], Z[6], Z[7]);
    zo[2] = make_float4(Z[8], Z[9], Z[10], Z[11]);
    zo[3] = make_float4(Z[12], Z[13], Z[14], Z[15]);
  }
  #pragma unroll
  for (int i = 0; i < 16; ++i) {
    float s0 = ts0[i], s1 = ts1[i];
    for (int off = 32; off > 0; off >>= 1) {
      s0 += __shfl_down(s0, off, 64);
      s1 += __shfl_down(s1, off, 64);
    }
    if (lane == 0) {
      atomicAdd(&statsP[1216 + (blockIdx.x & 7) * 128 + q0 + i], s0);
      atomicAdd(&statsP[1216 + (blockIdx.x & 7) * 128 + 64 + q0 + i], s1);
    }
  }
}

// -------------------------------------------- K2b: finalize BN2 affine (tiny)
__global__ void k_aff(const float* __restrict__ g2, const float* __restrict__ be2,
                      float* __restrict__ statsP) {
  const int o = threadIdx.x;
  if (o < 64) {
    float u0 = 0.f, u1 = 0.f;
    #pragma unroll
    for (int sl = 0; sl < 8; ++sl) {
      u0 += statsP[1216 + sl * 128 + o];
      u1 += statsP[1216 + sl * 128 + 64 + o];
    }
    const float m2 = u0 * INV_N;
    const float va = u1 * INV_N - m2 * m2;
    const float sc = g2[o] * rsqrtf(va + 1e-5f);
    statsP[2368 + o] = sc;
    statsP[2432 + o] = be2[o] - m2 * sc;
  }
}

// ------------------------------------------------- K3: S/first/last reduction
// lane = t (per-lane float4 loads of y-row and z2-row; aff/w1 via scalar pipe)
__global__ __launch_bounds__(256) void k_sfl(const float* __restrict__ y,
    const float* __restrict__ z2, const float* __restrict__ statsP,
    const float* __restrict__ w1,
    float* __restrict__ S, float* __restrict__ F, float* __restrict__ L) {
  const int b = blockIdx.y, v = blockIdx.x;
  const int lane = threadIdx.x & 63;
  const int wq   = __builtin_amdgcn_readfirstlane(threadIdx.x >> 6);
  float acc[64];
  #pragma unroll
  for (int i = 0; i < 64; ++i) acc[i] = 0.f;
  __shared__ float red[4][64];
  #pragma unroll
  for (int j = 0; j < 2; ++j) {
    const int t = wq * 128 + lane * 2 + j;
    const size_t row = ((size_t)(b * T_ + t)) * V_ + v;
    float yv[16];
    { const float4* yp = (const float4*)(y + row * 16);
      const float4 a0 = yp[0], a1 = yp[1], a2 = yp[2], a3 = yp[3];
      yv[0]=a0.x; yv[1]=a0.y; yv[2]=a0.z; yv[3]=a0.w;
      yv[4]=a1.x; yv[5]=a1.y; yv[6]=a1.z; yv[7]=a1.w;
      yv[8]=a2.x; yv[9]=a2.y; yv[10]=a2.z; yv[11]=a2.w;
      yv[12]=a3.x; yv[13]=a3.y; yv[14]=a3.z; yv[15]=a3.w; }
    #pragma unroll
    for (int cq = 0; cq < 16; ++cq) {
      const float4 z2v = *(const float4*)(z2 + row * 64 + cq * 4);
      #pragma unroll
      for (int jj = 0; jj < 4; ++jj) {
        const int ch = cq * 4 + jj;
        float z1 = 0.f;
        #pragma unroll
        for (int k = 0; k < 16; ++k) z1 += yv[k] * w1[k * 64 + ch];
        const float x1 = fmaxf(z1 * statsP[2240 + ch] + statsP[2304 + ch], 0.f);
        const float zz = (jj == 0) ? z2v.x : (jj == 1) ? z2v.y : (jj == 2) ? z2v.z : z2v.w;
        const float x2 = fmaxf(zz * statsP[2368 + ch] + statsP[2432 + ch], 0.f);
        const float xs = x1 + x2;
        acc[ch] += xs;
        if (t == 0)        F[(b * V_ + v) * 64 + ch] = xs;
        if (t == T_ - 1)   L[(b * V_ + v) * 64 + ch] = xs;
      }
    }
  }
  #pragma unroll
  for (int ch = 0; ch < 64; ++ch) {
    float s = acc[ch];
    #pragma unroll
    for (int m = 1; m <= 32; m <<= 1) s += __shfl_xor(s, m, 64);
    acc[ch] = s;
  }
  if (lane == 0) {
    #pragma unroll
    for (int ch = 0; ch < 64; ++ch) red[wq][ch] = acc[ch];
  }
  __syncthreads();
  if (threadIdx.x < 64)
    S[(b * V_ + v) * 64 + threadIdx.x] = red[0][threadIdx.x] + red[1][threadIdx.x] +
                                         red[2][threadIdx.x] + red[3][threadIdx.x];
}

// ------------------------------ K4: folded conv+mean, twt read exactly once
__global__ __launch_bounds__(256) void k_pool(const float* __restrict__ S,
    const float* __restrict__ F, const float* __restrict__ L,
    const float* __restrict__ twt, float* __restrict__ mp) {
  const int cog = blockIdx.x;   // 0..15
  const int kc  = blockIdx.y;   // 0..15
  const int ci0 = kc * 256;
  __shared__ float a_s[3][16 * 260];
  for (int f4 = threadIdx.x; f4 < 3072; f4 += 256) {
    const int arr = f4 >> 10;
    const int rem = f4 & 1023;
    const int bb  = rem >> 6;
    const int ci4 = rem & 63;
    const float4 sv = *(const float4*)&S[bb * 4096 + ci0 + ci4 * 4];
    float4 o;
    if (arr == 0) {
      const float4 lv = *(const float4*)&L[bb * 4096 + ci0 + ci4 * 4];
      o = make_float4(sv.x - lv.x, sv.y - lv.y, sv.z - lv.z, sv.w - lv.w);
    } else if (arr == 1) {
      o = sv;
    } else {
      const float4 fvv = *(const float4*)&F[bb * 4096 + ci0 + ci4 * 4];
      o = make_float4(sv.x - fvv.x, sv.y - fvv.y, sv.z - fvv.z, sv.w - fvv.w);
    }
    *(float4*)&a_s[arr][bb * 260 + ci4 * 4] = o;
  }
  __syncthreads();
  const int bb   = threadIdx.x & 15;
  const int co   = threadIdx.x >> 4;
  const int co_g = cog * 16 + co;
  float acc = 0.f;
  for (int ci4 = 0; ci4 < 64; ++ci4) {
    const float4 a0 = *(const float4*)&a_s[0][bb * 260 + ci4 * 4];
    const float4 a1 = *(const float4*)&a_s[1][bb * 260 + ci4 * 4];
    const float4 a2 = *(const float4*)&a_s[2][bb * 260 + ci4 * 4];
    const float4* tp = (const float4*)(twt + ((size_t)co_g * 4096 + ci0 + ci4 * 4) * 3);
    const float4 f0 = tp[0], f1 = tp[1], f2 = tp[2];
    acc += f0.x * a0.x + f0.y * a1.x + f0.z * a2.x
         + f0.w * a0.y + f1.x * a1.y + f1.y * a2.y
         + f1.z * a0.z + f1.w * a1.z + f2.x * a2.z
         + f2.y * a0.w + f2.z * a1.w + f2.w * a2.w;
  }
  mp[kc * 4096 + bb * 256 + co_g] = acc;
}

// ------------------------------------------- K5: fold K-partials + FC head
__global__ __launch_bounds__(128) void k_head(const float* __restrict__ mp,
    const float* __restrict__ tb, const float* __restrict__ f1w,
    const float* __restrict__ f1b, const float* __restrict__ f2w,
    const float* __restrict__ f2b, float* __restrict__ out) {
  const int b = blockIdx.x;
  __shared__ float ms[256];
  __shared__ float hs[128];
  for (int co = threadIdx.x; co < 256; co += 128) {
    float s = 0.f;
    #pragma unroll
    for (int kc = 0; kc < 16; ++kc) s += mp[kc * 4096 + b * 256 + co];
    ms[co] = s * INV_T + tb[co];
  }
  __syncthreads();
  {
    const int j = threadIdx.x;
    float acc = f1b[j];
    #pragma unroll 8
    for (int k = 0; k < 256; ++k) acc += ms[k] * f1w[k * 128 + j];
    hs[j] = fmaxf(acc, 0.f);
  }
  __syncthreads();
  if (threadIdx.x < NC_) {
    const int n = threadIdx.x;
    float acc = f2b[n];
    #pragma unroll 8
    for (int j = 0; j < 128; ++j) acc += hs[j] * f2w[j * NC_ + n];
    out[b * NC_ + n] = acc;
  }
}

extern "C" void kernel_launch(void* const* d_in, const int* in_sizes, int n_in,
                              void* d_out, int out_size, void* d_ws, size_t ws_size,
                              hipStream_t stream) {
  const float* x   = (const float*)d_in[0];
  const float* adj = (const float*)d_in[1];
  const float* w1  = (const float*)d_in[2];
  const float* b1  = (const float*)d_in[3];
  const float* g1  = (const float*)d_in[4];
  const float* be1 = (const float*)d_in[5];
  const float* w2  = (const float*)d_in[6];
  const float* b2  = (const float*)d_in[7];
  const float* g2  = (const float*)d_in[8];
  const float* be2 = (const float*)d_in[9];
  const float* twt = (const float*)d_in[10];
  const float* tb  = (const float*)d_in[11];
  const float* f1w = (const float*)d_in[12];
  const float* f1b = (const float*)d_in[13];
  const float* f2w = (const float*)d_in[14];
  const float* f2b = (const float*)d_in[15];
  float* out = (float*)d_out;
  float* ws  = (float*)d_ws;

  // workspace layout (floats), total ~169 MB
  float* AnT    = ws;                    // 65536
  float* statsP = ws + 65536;            // 2560 reserved (2496 used)
  float* S      = ws + 68096;            // 65536
  float* F      = ws + 133632;           // 65536
  float* L      = ws + 199168;           // 65536
  float* mp     = ws + 264704;           // 65536
  float* y      = ws + 330240;           // 8388608
  float* z2     = y + (size_t)B_ * T_ * V_ * C1_;  // 33554432

  hipLaunchKernelGGL(k_adjnorm, dim3(B_), dim3(256), 0, stream, adj, AnT, statsP);
  hipLaunchKernelGGL(k_gcn1, dim3(T_ / 8, B_), dim3(256), 0, stream, x, AnT, y);
  hipLaunchKernelGGL(k_gram, dim3(512), dim3(256), 0, stream, y, statsP);
  hipLaunchKernelGGL(k_gcn2, dim3(T_ / 8, B_), dim3(256), 0, stream,
                     y, AnT, w1, b1, g1, be1, w2, b2, statsP, z2);
  hipLaunchKernelGGL(k_aff, dim3(1), dim3(64), 0, stream, g2, be2, statsP);
  hipLaunchKernelGGL(k_sfl, dim3(V_, B_), dim3(256), 0, stream,
                     y, z2, statsP, w1, S, F, L);
  hipLaunchKernelGGL(k_pool, dim3(16, 16), dim3(256), 0, stream, S, F, L, twt, mp);
  hipLaunchKernelGGL(k_head, dim3(B_), dim3(128), 0, stream, mp, tb, f1w, f1b, f2w, f2b, out);
}

// Round 9
// 494.659 us; speedup vs baseline: 1.6702x; 1.6702x over previous
//
#include <hip/hip_runtime.h>

#define B_   16
#define T_   512
#define V_   64
#define C1_  16
#define H_   64
#define TC_  256
#define NC_  10
#define INV_N (1.0f/524288.0f)   // 1/(B*T*V)
#define INV_T (1.0f/512.0f)

// statsP layout (floats):
//   [0 .. 1215]    8 slots x 152: {sumy[16], G[136] packed upper-tri (c-major, d>=c)}
//   [1216 .. 2239] 8 slots x 128: BN2 partials {sum[64], sumsq[64]}
//   [2240..2303] aff1 scale   [2304..2367] aff1 shift   (written by k_gcn2)
//   [2368..2431] aff2 scale   [2432..2495] aff2 shift   (written by k_aff)

// ---------------------------------------------------------------- K0: adj_norm
__global__ __launch_bounds__(256) void k_adjnorm(const float* __restrict__ adj,
                                                 float* __restrict__ AnT,
                                                 float* __restrict__ statsP) {
  const int b = blockIdx.x;
  __shared__ float As[4096];
  __shared__ float dis[64];
  for (int idx = threadIdx.x; idx < 4096; idx += 256) As[idx] = adj[b * 4096 + idx];
  __syncthreads();
  if (threadIdx.x < 64) {
    const int v = threadIdx.x;
    float s = 0.f;
    #pragma unroll 8
    for (int w = 0; w < 64; ++w) s += As[v * 64 + ((w + v) & 63)];  // bank-fanned
    dis[v] = rsqrtf(s + 1e-6f);
  }
  __syncthreads();
  for (int idx = threadIdx.x; idx < 4096; idx += 256) {
    const int v = idx >> 6, w = idx & 63;
    AnT[b * 4096 + w * 64 + v] = dis[v] * As[v * 64 + w] * dis[w];
  }
  if (threadIdx.x < 140) statsP[b * 140 + threadIdx.x] = 0.f;   // zero [0,2240)
}

// ---------------------------------------------------------- K1: y = An@x (16ch)
__global__ __launch_bounds__(256) void k_gcn1(const float* __restrict__ x,
    const float* __restrict__ AnT, float* __restrict__ y) {
  const int b    = blockIdx.y;
  const int lane = threadIdx.x & 63;
  const int wq   = __builtin_amdgcn_readfirstlane(threadIdx.x >> 6);
  const float* __restrict__ At = AnT + b * 4096;
  for (int k = 0; k < 2; ++k) {
    const int t = blockIdx.x * 8 + wq * 2 + k;
    const float* __restrict__ xt = x + ((size_t)(b * T_ + t)) * V_ * C1_;
    float Y[16];
    #pragma unroll
    for (int i = 0; i < 16; ++i) Y[i] = 0.f;
    for (int w = 0; w < V_; ++w) {
      const float a = At[w * 64 + lane];
      const float* __restrict__ xr = xt + w * C1_;   // wave-uniform row
      #pragma unroll
      for (int c = 0; c < 16; ++c) Y[c] += a * xr[c];
    }
    float4* yo = (float4*)(y + (((size_t)(b * T_ + t)) * V_ + lane) * C1_);
    yo[0] = make_float4(Y[0], Y[1], Y[2], Y[3]);
    yo[1] = make_float4(Y[4], Y[5], Y[6], Y[7]);
    yo[2] = make_float4(Y[8], Y[9], Y[10], Y[11]);
    yo[3] = make_float4(Y[12], Y[13], Y[14], Y[15]);
  }
}

// ----------------------------- K1b: Gram stats. G = sum_rows y y^T, sumy.
// LDS-staged: block stages 64 rows; thread p<136 owns ONE pair (c,d), threads
// 136..151 own one sumy channel. 1 accumulator/thread -> no spill (r4 lesson:
// 152 per-thread accumulators spilled to scratch, 345us).
__global__ __launch_bounds__(256) void k_gram(const float* __restrict__ y,
                                              float* __restrict__ statsP) {
  __shared__ float Ys[64 * 17];
  const int tid = threadIdx.x;
  // decode flat pair index -> (c,d), d>=c, c-major (matches k_gcn2 unpack)
  int c = 0, rem = (tid < 136) ? tid : 0;
  while (rem >= 16 - c) { rem -= 16 - c; ++c; }
  const int d = c + rem;
  const int syc = tid - 136;

  float acc = 0.f;
  const float* __restrict__ base = y + (size_t)blockIdx.x * 8192;  // 512 rows
  for (int s = 0; s < 8; ++s) {
    const float4 vv = *(const float4*)(base + s * 1024 + tid * 4);
    __syncthreads();                       // previous stage's readers done
    const int rl = tid >> 2, c0 = (tid & 3) * 4;
    Ys[rl * 17 + c0 + 0] = vv.x;
    Ys[rl * 17 + c0 + 1] = vv.y;
    Ys[rl * 17 + c0 + 2] = vv.z;
    Ys[rl * 17 + c0 + 3] = vv.w;
    __syncthreads();                       // stage ready
    if (tid < 136) {
      #pragma unroll 8
      for (int r = 0; r < 64; ++r) acc += Ys[r * 17 + c] * Ys[r * 17 + d];
    } else if (tid < 152) {
      #pragma unroll 8
      for (int r = 0; r < 64; ++r) acc += Ys[r * 17 + syc];
    }
  }
  if (tid < 152) {
    const int idx = (tid < 136) ? (16 + tid) : syc;   // sy at [0,16), G at [16,152)
    atomicAdd(&statsP[(blockIdx.x & 7) * 152 + idx], acc);
  }
}

// ---------------------------------------------------------------- K2: layer 2
__global__ __launch_bounds__(256) void k_gcn2(const float* __restrict__ y,
    const float* __restrict__ AnT, const float* __restrict__ w1,
    const float* __restrict__ b1, const float* __restrict__ g1,
    const float* __restrict__ be1, const float* __restrict__ w2,
    const float* __restrict__ b2, float* __restrict__ statsP,
    float* __restrict__ z2) {
  __shared__ float ybuf[64 * 17];     // 4.25 KB
  __shared__ float sbuf[64 * 65];     // 16.25 KB (x1, then P^T)
  __shared__ float gtot[152];
  __shared__ float affl[128];
  const int b    = blockIdx.y;
  const int t0   = blockIdx.x * 8;
  const int lane = threadIdx.x & 63;
  const int wq   = __builtin_amdgcn_readfirstlane(threadIdx.x >> 6);
  const int q0   = wq * 16;

  // ---- prologue: fold G partials -> aff1 (var = w^T G w/N - (lin/N)^2)
  for (int i = threadIdx.x; i < 152; i += 256) {
    float s = 0.f;
    #pragma unroll
    for (int sl = 0; sl < 8; ++sl) s += statsP[sl * 152 + i];
    gtot[i] = s;
  }
  __syncthreads();
  if (threadIdx.x < 64) {
    const int o = threadIdx.x;
    float wv[16];
    #pragma unroll
    for (int c = 0; c < 16; ++c) wv[c] = w1[c * 64 + o];
    float lin = 0.f;
    #pragma unroll
    for (int c = 0; c < 16; ++c) lin += gtot[c] * wv[c];
    float qd = 0.f;
    int idx = 16;
    #pragma unroll
    for (int c = 0; c < 16; ++c) {
      qd += gtot[idx] * wv[c] * wv[c]; ++idx;
      #pragma unroll
      for (int d = c + 1; d < 16; ++d) { qd += 2.f * gtot[idx] * wv[c] * wv[d]; ++idx; }
    }
    const float linN = lin * INV_N;
    const float mean = linN + b1[o];
    const float var  = qd * INV_N - linN * linN;
    const float sc   = g1[o] * rsqrtf(var + 1e-5f);
    const float sh   = be1[o] - mean * sc;
    affl[o] = sc; affl[64 + o] = sh;
    statsP[2240 + o] = sc; statsP[2304 + o] = sh;   // cache for k_sfl
  }
  __syncthreads();
  float asc[16], ash[16];
  #pragma unroll
  for (int i = 0; i < 16; ++i) { asc[i] = affl[q0 + i]; ash[i] = affl[64 + q0 + i]; }

  const float* __restrict__ At = AnT + b * 4096;
  float ts0[16], ts1[16];
  #pragma unroll
  for (int i = 0; i < 16; ++i) { ts0[i] = 0.f; ts1[i] = 0.f; }

  for (int tt = 0; tt < 8; ++tt) {
    const int t = t0 + tt;
    const float4 yv4 = *(const float4*)(y + ((size_t)(b * T_ + t)) * 1024 + threadIdx.x * 4);
    __syncthreads();                                  // prev readers of bufs done
    { const int w = threadIdx.x >> 2, c0 = (threadIdx.x & 3) * 4;
      ybuf[w * 17 + c0 + 0] = yv4.x;
      ybuf[w * 17 + c0 + 1] = yv4.y;
      ybuf[w * 17 + c0 + 2] = yv4.z;
      ybuf[w * 17 + c0 + 3] = yv4.w; }
    __syncthreads();                                  // ybuf ready
    float z[16];
    #pragma unroll
    for (int i = 0; i < 16; ++i) z[i] = 0.f;
    #pragma unroll
    for (int k = 0; k < 16; ++k) {
      const float yk = ybuf[lane * 17 + k];
      #pragma unroll
      for (int i = 0; i < 16; ++i) z[i] += yk * w1[k * 64 + q0 + i];
    }
    #pragma unroll
    for (int i = 0; i < 16; ++i)
      sbuf[lane * 65 + q0 + i] = fmaxf(z[i] * asc[i] + ash[i], 0.f);
    __syncthreads();                                  // x1 ready
    float P[16];
    #pragma unroll
    for (int i = 0; i < 16; ++i) P[i] = 0.f;
    for (int w = 0; w < 64; ++w) {
      const float xv = sbuf[w * 65 + lane];
      #pragma unroll
      for (int i = 0; i < 16; ++i) P[i] += At[w * 64 + q0 + i] * xv;
    }
    __syncthreads();                                  // all x1 reads done
    #pragma unroll
    for (int i = 0; i < 16; ++i) sbuf[(q0 + i) * 65 + lane] = P[i];
    __syncthreads();                                  // P ready
    float Z[16];
    #pragma unroll
    for (int i = 0; i < 16; ++i) Z[i] = b2[q0 + i];
    for (int c = 0; c < 64; ++c) {
      const float p = sbuf[lane * 65 + c];
      #pragma unroll
      for (int i = 0; i < 16; ++i) Z[i] += w2[c * 64 + q0 + i] * p;
    }
    #pragma unroll
    for (int i = 0; i < 16; ++i) { const float v = Z[i]; ts0[i] += v; ts1[i] += v * v; }
    float4* zo = (float4*)(z2 + (((size_t)(b * T_ + t)) * V_ + lane) * H_ + q0);
    zo[0] = make_float4(Z[0], Z[1], Z[2], Z[3]);
    zo[1] = make_float4(Z[4], Z[5], Z[6], Z[7]);
    zo[2] = make_float4(Z[8], Z[9], Z[10], Z[11]);
    zo[3] = make_float4(Z[12], Z[13], Z[14], Z[15]);
  }
  #pragma unroll
  for (int i = 0; i < 16; ++i) {
    float s0 = ts0[i], s1 = ts1[i];
    for (int off = 32; off > 0; off >>= 1) {
      s0 += __shfl_down(s0, off, 64);
      s1 += __shfl_down(s1, off, 64);
    }
    if (lane == 0) {
      atomicAdd(&statsP[1216 + (blockIdx.x & 7) * 128 + q0 + i], s0);
      atomicAdd(&statsP[1216 + (blockIdx.x & 7) * 128 + 64 + q0 + i], s1);
    }
  }
}

// -------------------------------------------- K2b: finalize BN2 affine (tiny)
__global__ void k_aff(const float* __restrict__ g2, const float* __restrict__ be2,
                      float* __restrict__ statsP) {
  const int o = threadIdx.x;
  if (o < 64) {
    float u0 = 0.f, u1 = 0.f;
    #pragma unroll
    for (int sl = 0; sl < 8; ++sl) {
      u0 += statsP[1216 + sl * 128 + o];
      u1 += statsP[1216 + sl * 128 + 64 + o];
    }
    const float m2 = u0 * INV_N;
    const float va = u1 * INV_N - m2 * m2;
    const float sc = g2[o] * rsqrtf(va + 1e-5f);
    statsP[2368 + o] = sc;
    statsP[2432 + o] = be2[o] - m2 * sc;
  }
}

// ------------------------------------------------- K3: S/first/last reduction
// Wave wq owns channel quadrant [16wq,16wq+16); lane = t. acc[16] only (no
// spill), 96 shuffles total, disjoint S/F/L quadrant writes (no LDS).
__global__ __launch_bounds__(256) void k_sfl(const float* __restrict__ y,
    const float* __restrict__ z2, const float* __restrict__ statsP,
    const float* __restrict__ w1,
    float* __restrict__ S, float* __restrict__ F, float* __restrict__ L) {
  const int b = blockIdx.y, v = blockIdx.x;
  const int lane = threadIdx.x & 63;
  const int wq   = __builtin_amdgcn_readfirstlane(threadIdx.x >> 6);
  const int ch0  = wq * 16;
  float acc[16];
  #pragma unroll
  for (int i = 0; i < 16; ++i) acc[i] = 0.f;
  for (int i = 0; i < 8; ++i) {
    const int t = i * 64 + lane;
    const size_t row = ((size_t)(b * T_ + t)) * V_ + v;
    float yv[16];
    { const float4* yp = (const float4*)(y + row * 16);
      const float4 a0 = yp[0], a1 = yp[1], a2 = yp[2], a3 = yp[3];
      yv[0]=a0.x; yv[1]=a0.y; yv[2]=a0.z; yv[3]=a0.w;
      yv[4]=a1.x; yv[5]=a1.y; yv[6]=a1.z; yv[7]=a1.w;
      yv[8]=a2.x; yv[9]=a2.y; yv[10]=a2.z; yv[11]=a2.w;
      yv[12]=a3.x; yv[13]=a3.y; yv[14]=a3.z; yv[15]=a3.w; }
    float x2v[16];
    { const float4* zp = (const float4*)(z2 + row * 64 + ch0);
      const float4 b0 = zp[0], b1v = zp[1], b2v = zp[2], b3 = zp[3];
      x2v[0]=b0.x; x2v[1]=b0.y; x2v[2]=b0.z; x2v[3]=b0.w;
      x2v[4]=b1v.x; x2v[5]=b1v.y; x2v[6]=b1v.z; x2v[7]=b1v.w;
      x2v[8]=b2v.x; x2v[9]=b2v.y; x2v[10]=b2v.z; x2v[11]=b2v.w;
      x2v[12]=b3.x; x2v[13]=b3.y; x2v[14]=b3.z; x2v[15]=b3.w; }
    #pragma unroll
    for (int j = 0; j < 16; ++j) {
      const int ch = ch0 + j;
      float z1 = 0.f;
      #pragma unroll
      for (int k = 0; k < 16; ++k) z1 += yv[k] * w1[k * 64 + ch];   // uniform
      const float x1 = fmaxf(z1 * statsP[2240 + ch] + statsP[2304 + ch], 0.f);
      const float x2 = fmaxf(x2v[j] * statsP[2368 + ch] + statsP[2432 + ch], 0.f);
      const float xs = x1 + x2;
      acc[j] += xs;
      if (t == 0)        F[(b * V_ + v) * 64 + ch] = xs;
      if (t == T_ - 1)   L[(b * V_ + v) * 64 + ch] = xs;
    }
  }
  #pragma unroll
  for (int j = 0; j < 16; ++j) {
    float s = acc[j];
    #pragma unroll
    for (int m = 1; m <= 32; m <<= 1) s += __shfl_xor(s, m, 64);
    if (lane == 0) S[(b * V_ + v) * 64 + ch0 + j] = s;
  }
}

// ------------------------------ K4: folded conv+mean, twt read exactly once
__global__ __launch_bounds__(256) void k_pool(const float* __restrict__ S,
    const float* __restrict__ F, const float* __restrict__ L,
    const float* __restrict__ twt, float* __restrict__ mp) {
  const int cog = blockIdx.x;   // 0..15
  const int kc  = blockIdx.y;   // 0..15
  const int ci0 = kc * 256;
  __shared__ float a_s[3][16 * 260];
  for (int f4 = threadIdx.x; f4 < 3072; f4 += 256) {
    const int arr = f4 >> 10;
    const int rem = f4 & 1023;
    const int bb  = rem >> 6;
    const int ci4 = rem & 63;
    const float4 sv = *(const float4*)&S[bb * 4096 + ci0 + ci4 * 4];
    float4 o;
    if (arr == 0) {
      const float4 lv = *(const float4*)&L[bb * 4096 + ci0 + ci4 * 4];
      o = make_float4(sv.x - lv.x, sv.y - lv.y, sv.z - lv.z, sv.w - lv.w);
    } else if (arr == 1) {
      o = sv;
    } else {
      const float4 fvv = *(const float4*)&F[bb * 4096 + ci0 + ci4 * 4];
      o = make_float4(sv.x - fvv.x, sv.y - fvv.y, sv.z - fvv.z, sv.w - fvv.w);
    }
    *(float4*)&a_s[arr][bb * 260 + ci4 * 4] = o;
  }
  __syncthreads();
  const int bb   = threadIdx.x & 15;
  const int co   = threadIdx.x >> 4;
  const int co_g = cog * 16 + co;
  float acc = 0.f;
  for (int ci4 = 0; ci4 < 64; ++ci4) {
    const float4 a0 = *(const float4*)&a_s[0][bb * 260 + ci4 * 4];
    const float4 a1 = *(const float4*)&a_s[1][bb * 260 + ci4 * 4];
    const float4 a2 = *(const float4*)&a_s[2][bb * 260 + ci4 * 4];
    const float4* tp = (const float4*)(twt + ((size_t)co_g * 4096 + ci0 + ci4 * 4) * 3);
    const float4 f0 = tp[0], f1 = tp[1], f2 = tp[2];
    acc += f0.x * a0.x + f0.y * a1.x + f0.z * a2.x
         + f0.w * a0.y + f1.x * a1.y + f1.y * a2.y
         + f1.z * a0.z + f1.w * a1.z + f2.x * a2.z
         + f2.y * a0.w + f2.z * a1.w + f2.w * a2.w;
  }
  mp[kc * 4096 + bb * 256 + co_g] = acc;
}

// ------------------------------------------- K5: fold K-partials + FC head
__global__ __launch_bounds__(128) void k_head(const float* __restrict__ mp,
    const float* __restrict__ tb, const float* __restrict__ f1w,
    const float* __restrict__ f1b, const float* __restrict__ f2w,
    const float* __restrict__ f2b, float* __restrict__ out) {
  const int b = blockIdx.x;
  __shared__ float ms[256];
  __shared__ float hs[128];
  for (int co = threadIdx.x; co < 256; co += 128) {
    float s = 0.f;
    #pragma unroll
    for (int kc = 0; kc < 16; ++kc) s += mp[kc * 4096 + b * 256 + co];
    ms[co] = s * INV_T + tb[co];
  }
  __syncthreads();
  {
    const int j = threadIdx.x;
    float acc = f1b[j];
    #pragma unroll 8
    for (int k = 0; k < 256; ++k) acc += ms[k] * f1w[k * 128 + j];
    hs[j] = fmaxf(acc, 0.f);
  }
  __syncthreads();
  if (threadIdx.x < NC_) {
    const int n = threadIdx.x;
    float acc = f2b[n];
    #pragma unroll 8
    for (int j = 0; j < 128; ++j) acc += hs[j] * f2w[j * NC_ + n];
    out[b * NC_ + n] = acc;
  }
}

extern "C" void kernel_launch(void* const* d_in, const int* in_sizes, int n_in,
                              void* d_out, int out_size, void* d_ws, size_t ws_size,
                              hipStream_t stream) {
  const float* x   = (const float*)d_in[0];
  const float* adj = (const float*)d_in[1];
  const float* w1  = (const float*)d_in[2];
  const float* b1  = (const float*)d_in[3];
  const float* g1  = (const float*)d_in[4];
  const float* be1 = (const float*)d_in[5];
  const float* w2  = (const float*)d_in[6];
  const float* b2  = (const float*)d_in[7];
  const float* g2  = (const float*)d_in[8];
  const float* be2 = (const float*)d_in[9];
  const float* twt = (const float*)d_in[10];
  const float* tb  = (const float*)d_in[11];
  const float* f1w = (const float*)d_in[12];
  const float* f1b = (const float*)d_in[13];
  const float* f2w = (const float*)d_in[14];
  const float* f2b = (const float*)d_in[15];
  float* out = (float*)d_out;
  float* ws  = (float*)d_ws;

  // workspace layout (floats), total ~169 MB
  float* AnT    = ws;                    // 65536
  float* statsP = ws + 65536;            // 2560 reserved (2496 used)
  float* S      = ws + 68096;            // 65536
  float* F      = ws + 133632;           // 65536
  float* L      = ws + 199168;           // 65536
  float* mp     = ws + 264704;           // 65536
  float* y      = ws + 330240;           // 8388608
  float* z2     = y + (size_t)B_ * T_ * V_ * C1_;  // 33554432

  hipLaunchKernelGGL(k_adjnorm, dim3(B_), dim3(256), 0, stream, adj, AnT, statsP);
  hipLaunchKernelGGL(k_gcn1, dim3(T_ / 8, B_), dim3(256), 0, stream, x, AnT, y);
  hipLaunchKernelGGL(k_gram, dim3(1024), dim3(256), 0, stream, y, statsP);
  hipLaunchKernelGGL(k_gcn2, dim3(T_ / 8, B_), dim3(256), 0, stream,
                     y, AnT, w1, b1, g1, be1, w2, b2, statsP, z2);
  hipLaunchKernelGGL(k_aff, dim3(1), dim3(64), 0, stream, g2, be2, statsP);
  hipLaunchKernelGGL(k_sfl, dim3(V_, B_), dim3(256), 0, stream,
                     y, z2, statsP, w1, S, F, L);
  hipLaunchKernelGGL(k_pool, dim3(16, 16), dim3(256), 0, stream, S, F, L, twt, mp);
  hipLaunchKernelGGL(k_head, dim3(B_), dim3(128), 0, stream, mp, tb, f1w, f1b, f2w, f2b, out);
}